// Round 6
// baseline (404.973 us; speedup 1.0000x reference)
//
#include <hip/hip_runtime.h>

// ---------------- problem constants ----------------
#define NVEC  131072      // 32*4096 vectors
#define DIM   64
#define K     512
#define DECAYF 0.99f
#define OMDF   0.01f
#define EPSF   1e-5f
#define NBLK_ASSIGN (NVEC / 64)   // 2048 blocks, 64 vectors each

// ---------------- output layout (floats, concatenated in return order) ----
#define Q_OFF    0
#define DIFF_OFF 8388608
#define IND_OFF  8388609
#define NE_OFF   8519681
#define NCS_OFF  8552449
#define NEA_OFF  8552961

// ---------------- ws layout (floats) — total ~0.8 MB ----
#define ET_OFF    0        // E^T : K x DIM
#define C_OFF     32768    // np-order sum(E*E, axis=0) : K
#define CNT_OFF   33280    // counts : K  (global fp atomics, zeroed each call)
#define ESUM_OFF  33792    // segment sum : K x DIM
#define DPART_OFF 66560    // per-assign-block diff partials : 2048
#define BASE_OFF  68608    // bucket base per code : 512 (int)
#define CUR_OFF   69120    // bucket cursors : 512 (int)
#define BUCK_OFF  69632    // bucketed vector ids : NVEC (int)

// ============ prep: transpose embed -> E^T, C_j = np.sum(E*E, axis=0) ====
__global__ __launch_bounds__(256) void vq_prep(const float* __restrict__ embed,
                                               float* __restrict__ ws) {
    #pragma clang fp contract(off)
    int j = blockIdx.x * 256 + threadIdx.x;
    float c = 0.0f;
    for (int d = 0; d < DIM; ++d) {
        float v = embed[d * K + j];           // coalesced across j
        ws[ET_OFF + j * DIM + d] = v;
        float t = v * v;
        c = c + t;
    }
    ws[C_OFF + j] = c;
}

// ============ main: np-fp32-replica argmin, 4-way K-split ================
// Block = 4 waves x 64 vectors; wave w scans codes [w*128,(w+1)*128).
// asm clobber pins f[64] in VGPRs — r4/r5 compiled to 40 VGPRs and
// rematerialized x loads from L1 inside the j-loop (1.8x slowdown).
__global__ __launch_bounds__(256, 4) void vq_assign(
    const float* __restrict__ x,
    const float* __restrict__ ET,      // ws + ET_OFF
    const float* __restrict__ C,       // ws + C_OFF
    float* __restrict__ counts,        // ws + CNT_OFF (zeroed)
    float* __restrict__ dpart,         // ws + DPART_OFF
    float* __restrict__ out)
{
    #pragma clang fp contract(off)
    __shared__ float sd[4][64];
    __shared__ int   si[4][64];
    __shared__ int   sbest[64];
    __shared__ float wdl[4];

    int lane = threadIdx.x & 63;
    int wq   = __builtin_amdgcn_readfirstlane(threadIdx.x >> 6); // wave-uniform
    int v    = blockIdx.x * 64 + lane;
    const float* fx = x + (size_t)v * DIM;

    float f[DIM];
    #pragma unroll
    for (int k = 0; k < DIM / 4; ++k) {
        float4 t = ((const float4*)fx)[k];
        f[4*k+0] = t.x; f[4*k+1] = t.y; f[4*k+2] = t.z; f[4*k+3] = t.w;
    }
    // pin every f[d] in a VGPR; compiler can no longer re-fold the loads
    #pragma unroll
    for (int d = 0; d < DIM; ++d) asm volatile("" : "+v"(f[d]));

    // A = np.sum(f*f, axis=1): numpy pairwise, n=64 -> 8 accumulators over
    // strides of 8, then ((r0+r1)+(r2+r3))+((r4+r5)+(r6+r7)). Plain mul+add.
    float r[8];
    #pragma unroll
    for (int k = 0; k < 8; ++k) r[k] = f[k] * f[k];
    #pragma unroll
    for (int b = 1; b < 8; ++b) {
        #pragma unroll
        for (int k = 0; k < 8; ++k) {
            float t = f[8*b + k] * f[8*b + k];
            r[k] = r[k] + t;
        }
    }
    float A = ((r[0] + r[1]) + (r[2] + r[3])) + ((r[4] + r[5]) + (r[6] + r[7]));

    // scan this wave's 128 codes; j wave-uniform -> scalar s_loads for e,C.
    // Per-j fp32 sequence bit-identical to round-2 passing kernel.
    const float* eseg = ET + (size_t)wq * 128 * DIM;
    const float* Cseg = C + wq * 128;
    float bestd = 3.0e38f;
    int   besti = wq * 128;
    #pragma unroll 4
    for (int jj = 0; jj < 128; ++jj) {
        const float* e = eseg + jj * DIM;
        float m = 0.0f;
        #pragma unroll
        for (int d = 0; d < DIM; ++d) m = __builtin_fmaf(f[d], e[d], m);
        float t1 = 2.0f * m;             // exact (x2)
        float t2 = A - t1;               // rounded at ulp(~64)
        float dist = t2 + Cseg[jj];      // rounded
        if (dist < bestd) { bestd = dist; besti = wq * 128 + jj; }
    }

    sd[wq][lane] = bestd;
    si[wq][lane] = besti;
    __syncthreads();

    if (wq == 0) {
        float bd = sd[0][lane];
        int   bi = si[0][lane];
        #pragma unroll
        for (int q = 1; q < 4; ++q) {
            float d2 = sd[q][lane];
            int   i2 = si[q][lane];
            if (d2 < bd || (d2 == bd && i2 < bi)) { bd = d2; bi = i2; }
        }
        sbest[lane] = bi;
        out[IND_OFF + v] = (float)bi;    // coalesced
        // histogram: fp adds of 1.0 are integer-exact -> order-independent
        atomicAdd(&counts[bi], 1.0f);
    }
    __syncthreads();

    // epilogue: wave w handles a 16-float quarter of each row
    int bi = sbest[lane];
    const float* qrow = ET + (size_t)bi * DIM + wq * 16;
    float* orow = out + Q_OFF + (size_t)v * DIM + wq * 16;
    float dl = 0.0f;
    #pragma unroll
    for (int k = 0; k < 4; ++k) {
        float4 tq = ((const float4*)qrow)[k];
        float r0 = tq.x - f[wq*16 + 4*k+0];
        float r1 = tq.y - f[wq*16 + 4*k+1];
        float r2 = tq.z - f[wq*16 + 4*k+2];
        float r3 = tq.w - f[wq*16 + 4*k+3];
        dl = __builtin_fmaf(r0, r0, dl); dl = __builtin_fmaf(r1, r1, dl);
        dl = __builtin_fmaf(r2, r2, dl); dl = __builtin_fmaf(r3, r3, dl);
        ((float4*)orow)[k] = tq;
    }

    #pragma unroll
    for (int off = 32; off > 0; off >>= 1) dl += __shfl_down(dl, off);
    if (lane == 0) wdl[wq] = dl;
    __syncthreads();
    if (threadIdx.x == 0)
        dpart[blockIdx.x] = ((wdl[0] + wdl[1]) + (wdl[2] + wdl[3]));
}

// ============ scan: exclusive scan of counts -> base + cursors ============
__global__ __launch_bounds__(512) void vq_scan(
    const float* __restrict__ counts,  // ws + CNT_OFF
    int* __restrict__ baseI,           // ws + BASE_OFF
    int* __restrict__ curI)            // ws + CUR_OFF
{
    __shared__ int sc[K];
    int j = threadIdx.x;
    int ci = (int)counts[j];
    sc[j] = ci;
    __syncthreads();
    for (int off = 1; off < K; off <<= 1) {
        int t = (j >= off) ? sc[j - off] : 0;
        __syncthreads();
        sc[j] += t;
        __syncthreads();
    }
    int base = sc[j] - ci;
    baseI[j] = base;
    curI[j]  = base;
}

// ============ bucket: grab slots via global atomic cursors ================
__global__ __launch_bounds__(256) void vq_bucket(
    const float* __restrict__ ind,
    int* __restrict__ curI,
    int* __restrict__ buckI)
{
    int v = blockIdx.x * 256 + threadIdx.x;
    int j = (int)ind[v];                   // coalesced
    int slot = atomicAdd(&curI[j], 1);
    buckI[slot] = v;                       // scattered 4B, L2-absorbed
}

// ============ esum: per-code gather-sum, ids staged through LDS ===========
// Block = code j, 4 waves; ids chunked into LDS so row loads pipeline
// (no serialized dependent scalar-load chain).
__global__ __launch_bounds__(256) void vq_esum(
    const float* __restrict__ x,
    const int* __restrict__ buckI,
    const int* __restrict__ baseI,
    const float* __restrict__ counts,
    float* __restrict__ esum)          // ws + ESUM_OFF
{
    __shared__ int   ids[512];
    __shared__ float p[4][DIM];
    int j = blockIdx.x;
    int t = threadIdx.x;
    int d = t & 63;
    int w = __builtin_amdgcn_readfirstlane(t >> 6);
    int beg = baseI[j];
    int cnt = (int)counts[j];

    float acc = 0.0f;
    for (int c0 = 0; c0 < cnt; c0 += 512) {
        int nc = min(512, cnt - c0);
        __syncthreads();
        for (int i = t; i < nc; i += 256) ids[i] = buckI[beg + c0 + i];
        __syncthreads();
        for (int r = w; r < nc; r += 4) {
            int v = ids[r];                          // LDS broadcast
            acc += x[(size_t)v * DIM + d];           // 256 B coalesced line
        }
    }
    p[w][d] = acc;
    __syncthreads();
    if (w == 0)
        esum[j * DIM + d] = ((p[0][d] + p[1][d]) + (p[2][d] + p[3][d]));
}

// ============ finalize: EMA updates + normalized codebook + diff ==========
__global__ __launch_bounds__(512) void vq_finalize(
    const float* __restrict__ cluster_size,
    const float* __restrict__ embed_avg,
    const float* __restrict__ ws,
    float* __restrict__ out)
{
    __shared__ float wsum[8];
    __shared__ float dsum_sh[8];
    __shared__ float n_sh;
    int j = threadIdx.x;  // 512 threads, one per code

    float ncs = DECAYF * cluster_size[j] + OMDF * ws[CNT_OFF + j];
    out[NCS_OFF + j] = ncs;

    // diff: sum 2048 block partials (deterministic)
    float dsum = 0.0f;
    #pragma unroll
    for (int k = 0; k < NBLK_ASSIGN / 512; ++k)
        dsum += ws[DPART_OFF + k * 512 + j];

    float s = ncs;
    #pragma unroll
    for (int off = 32; off > 0; off >>= 1) {
        s    += __shfl_down(s, off);
        dsum += __shfl_down(dsum, off);
    }
    if ((j & 63) == 0) { wsum[j >> 6] = s; dsum_sh[j >> 6] = dsum; }
    __syncthreads();
    if (j == 0) {
        float n = 0.f, dtot = 0.f;
        #pragma unroll
        for (int w = 0; w < 8; ++w) { n += wsum[w]; dtot += dsum_sh[w]; }
        n_sh = n;
        out[DIFF_OFF] = dtot * (1.0f / 8388608.0f);  // 2^23: exact
    }
    __syncthreads();
    float n   = n_sh;
    float csz = (ncs + EPSF) / (n + (float)K * EPSF) * n;

    #pragma unroll 4
    for (int d = 0; d < DIM; ++d) {
        float ea = DECAYF * embed_avg[d * K + j] + OMDF * ws[ESUM_OFF + j * DIM + d];
        out[NEA_OFF + d * K + j] = ea;        // coalesced over j
        out[NE_OFF  + d * K + j] = ea / csz;
    }
}

// ============ launch ============
extern "C" void kernel_launch(void* const* d_in, const int* in_sizes, int n_in,
                              void* d_out, int out_size, void* d_ws, size_t ws_size,
                              hipStream_t stream) {
    const float* x            = (const float*)d_in[0];
    const float* embed        = (const float*)d_in[1];
    const float* cluster_size = (const float*)d_in[2];
    const float* embed_avg    = (const float*)d_in[3];
    float* out = (float*)d_out;
    float* ws  = (float*)d_ws;

    int* baseI = (int*)(ws + BASE_OFF);
    int* curI  = (int*)(ws + CUR_OFF);
    int* buckI = (int*)(ws + BUCK_OFF);

    // zero the count accumulators (ws is poisoned 0xAA each call)
    hipMemsetAsync(ws + CNT_OFF, 0, K * sizeof(float), stream);

    vq_prep<<<K / 256, 256, 0, stream>>>(embed, ws);
    vq_assign<<<NBLK_ASSIGN, 256, 0, stream>>>(
        x, ws + ET_OFF, ws + C_OFF, ws + CNT_OFF, ws + DPART_OFF, out);
    vq_scan<<<1, 512, 0, stream>>>(ws + CNT_OFF, baseI, curI);
    vq_bucket<<<NVEC / 256, 256, 0, stream>>>(out + IND_OFF, curI, buckI);
    vq_esum<<<K, 256, 0, stream>>>(x, buckI, baseI, ws + CNT_OFF, ws + ESUM_OFF);
    vq_finalize<<<1, K, 0, stream>>>(cluster_size, embed_avg, ws, out);
}